// Round 3
// baseline (73.660 us; speedup 1.0000x reference)
//
#include <hip/hip_runtime.h>
#include <math.h>

#define N_CG   50000
#define APC    13
#define FEAT   128
#define DEG    16
#define VOCAB  100
#define TPAD   16              // padded row stride of T (floats) -> 64B rows
#define ZJT    16              // zj rows per prep block
#define NTILE  7               // ceil(VOCAB/ZJT)
#define TBLK   (VOCAB * NTILE) // 700 T-tile blocks
#define PACKB  ((N_CG + 255) / 256)
#define CG_PER_BLK 16

// Kernel 1, role A (blocks [0,700)): compute T tile with on-the-fly P rows.
//   zi = b/7 fixed, zj in [zj0, zj0+nrows). P rows (<=17) live in LDS only.
// Kernel 1, role B (blocks [700,896)): pack xyz4[i] = {x,y,z, bitcast(cg_z)}.
__global__ void prep_kernel(const float* __restrict__ xyz,
                            const int*   __restrict__ cg_z,
                            const float* __restrict__ emb,
                            const float* __restrict__ Wmsg,
                            const float* __restrict__ Wvec,
                            float*  __restrict__ T,
                            float4* __restrict__ xyz4) {
    int b = blockIdx.x;
    int t = threadIdx.x;
    if (b >= TBLK) {                       // role B: pack
        int i = (b - TBLK) * 256 + t;
        if (i < N_CG)
            xyz4[i] = make_float4(xyz[3*i], xyz[3*i+1], xyz[3*i+2],
                                  __int_as_float(cg_z[i]));
        return;
    }
    __shared__ float Pl[ZJT + 1][FEAT];    // rows 0..nrows-1: zj; row nrows: zi
    __shared__ float hs[ZJT][FEAT + 1];    // silu rows, padded

    int zi    = b / NTILE;
    int zj0   = (b % NTILE) * ZJT;
    int nrows = (VOCAB - zj0 < ZJT) ? (VOCAB - zj0) : ZJT;

    // P rows: task = r*128 + f; waves stay within one row (z uniform per wave)
    int ntask = (nrows + 1) * FEAT;
    for (int i = t; i < ntask; i += 256) {
        int r = i >> 7, f = i & 127;
        int z = (r == nrows) ? zi : (zj0 + r);
        float acc = 0.f;
        if (z != 0) {
            #pragma unroll 8
            for (int k = 0; k < FEAT; ++k)
                acc += emb[z * FEAT + k] * Wmsg[k * FEAT + f];
        }
        Pl[r][f] = acc;
    }
    __syncthreads();

    for (int i = t; i < nrows * FEAT; i += 256) {
        int r = i >> 7, f = i & 127;
        float h = Pl[nrows][f] + Pl[r][f];
        hs[r][f] = h / (1.f + expf(-h));   // silu
    }
    __syncthreads();

    if (t < nrows * APC) {
        int r = t / APC, c = t % APC;
        float s = 0.f;
        #pragma unroll 8
        for (int f = 0; f < FEAT; ++f)
            s += hs[r][f] * Wvec[f * APC + c];   // Wvec: f uniform per wave
        T[(size_t)(zi * VOCAB + zj0 + r) * TPAD + c] = s;
    }
}

// Kernel 2: fused segment-sum + reconstruction.
// Phase 1: 256 edges/block; ONE 16B xyz4 gather per edge; unit*inv and the
//   T row id packed into a float4 in LDS.
// Phase 2: (cg, channel) threads; broadcast ds_read_b128 + one T scalar
//   gather per edge. Output staged in LDS, written as aligned float4.
__global__ void recon_kernel(const float4* __restrict__ xyz4,
                             const int*    __restrict__ nbr,
                             const int*    __restrict__ ca_idx,
                             const float*  __restrict__ T,
                             float* __restrict__ out) {
    __shared__ float4 eu[CG_PER_BLK][DEG + 1];   // pad row -> conflict-free
    __shared__ float4 xis[CG_PER_BLK];
    __shared__ float  obuf[CG_PER_BLK * APC * 3];  // 624 floats = 2496B

    int t = threadIdx.x;
    int cg0 = blockIdx.x * CG_PER_BLK;

    {   // phase 1: one edge per thread
        int g = t >> 4, k = t & 15;
        int cg = cg0 + g;
        int e  = cg * DEG + k;                 // src = repeat(arange, DEG)
        int j  = nbr[2 * e + 1];
        float4 pj = xyz4[j];
        float4 pi = xyz4[cg];
        if (k == 0) xis[g] = pi;
        float dx = pj.x - pi.x, dy = pj.y - pi.y, dz = pj.z - pi.z;
        float inv = 1.f / (sqrtf(dx*dx + dy*dy + dz*dz) + 1e-8f);
        int row = __float_as_int(pi.w) * VOCAB + __float_as_int(pj.w);
        eu[g][k] = make_float4(dx*inv, dy*inv, dz*inv, __int_as_float(row));
    }
    __syncthreads();

    if (t < CG_PER_BLK * APC) {                // phase 2
        int g = t / APC, c = t % APC;
        float a0 = 0.f, a1 = 0.f, a2 = 0.f;
        #pragma unroll
        for (int k = 0; k < DEG; ++k) {
            float4 u = eu[g][k];
            int row = __float_as_int(u.w);
            float w = T[(size_t)row * TPAD + c];
            a0 += w * u.x; a1 += w * u.y; a2 += w * u.z;
        }
        int cg = cg0 + g;
        int czero = ca_idx[cg] - (cg * APC + 1); // channel of the ca atom - ...
        if (c == czero + 1 - 1 + 1 - 1 + (ca_idx[cg] - cg * APC - 1) * 0 &&
            c == ca_idx[cg] - cg * APC) { }      // (kept simple below)
        if (c == ca_idx[cg] - cg * APC) { a0 = 0.f; a1 = 0.f; a2 = 0.f; }
        float4 xi = xis[g];
        obuf[t * 3 + 0] = a0 + xi.x;
        obuf[t * 3 + 1] = a1 + xi.y;
        obuf[t * 3 + 2] = a2 + xi.z;
    }
    __syncthreads();

    if (t < (CG_PER_BLK * APC * 3) / 4) {      // 156 float4 = 2496B contiguous
        float4* ov = (float4*)(out + (size_t)blockIdx.x * (CG_PER_BLK * APC * 3));
        ov[t] = ((const float4*)obuf)[t];
    }
}

extern "C" void kernel_launch(void* const* d_in, const int* in_sizes, int n_in,
                              void* d_out, int out_size, void* d_ws, size_t ws_size,
                              hipStream_t stream) {
    const float* cg_xyz  = (const float*)d_in[0];
    const float* emb     = (const float*)d_in[1];
    const float* W_msg   = (const float*)d_in[2];
    const float* W_vec   = (const float*)d_in[3];
    const int*   cg_z    = (const int*)d_in[4];
    const int*   nbr     = (const int*)d_in[5];
    const int*   ca_idx  = (const int*)d_in[7];
    float* out = (float*)d_out;

    float*  T    = (float*)d_ws;                       // 10000*16*4 = 640 KB
    float4* xyz4 = (float4*)((char*)d_ws + (size_t)VOCAB * VOCAB * TPAD * 4);

    prep_kernel<<<TBLK + PACKB, 256, 0, stream>>>(
        cg_xyz, cg_z, emb, W_msg, W_vec, T, xyz4);
    recon_kernel<<<N_CG / CG_PER_BLK, 256, 0, stream>>>(
        xyz4, nbr, ca_idx, T, out);
}

// Round 4
// 31.789 us; speedup vs baseline: 2.3172x; 2.3172x over previous
//
#include <hip/hip_runtime.h>
#include <math.h>

#define N_CG   50000
#define APC    13
#define FEAT   128
#define DEG    16
#define VOCAB  100
#define TPAD   16              // padded row stride of T (floats) -> 64B rows
#define ROWS_PER_BLK 16        // table: rows per block
#define CG_PER_BLK 16          // recon: cgs per block
#define PBLK   (VOCAB / 2)     // 50 GEMM blocks (2 z-rows per 256-thread block)
#define PACKB  ((N_CG + 255) / 256)

// Kernel 1, role A (blocks [0,50)): P[z][f] = (z!=0 ? emb[z] : 0) @ W_msg.
//   2 z-rows per block (256 threads). Computed ONCE (1.6M MACs total).
// Kernel 1, role B (blocks [50,50+196)): pack xyz4[i]={x,y,z,bitcast(cg_z)}.
__global__ void p_pack_kernel(const float* __restrict__ emb,
                              const float* __restrict__ Wmsg,
                              const float* __restrict__ xyz,
                              const int*   __restrict__ cg_z,
                              float*  __restrict__ P,
                              float4* __restrict__ xyz4) {
    int b = blockIdx.x;
    int t = threadIdx.x;
    if (b < PBLK) {                        // role A: P GEMM
        int z = b * 2 + (t >> 7);          // wave-uniform z
        int f = t & 127;
        float acc = 0.f;
        if (z != 0) {
            #pragma unroll 8
            for (int k = 0; k < FEAT; ++k)
                acc += emb[z * FEAT + k] * Wmsg[k * FEAT + f];
        }
        P[z * FEAT + f] = acc;
        return;
    }
    int i = (b - PBLK) * 256 + t;          // role B: pack
    if (i < N_CG)
        xyz4[i] = make_float4(xyz[3*i], xyz[3*i+1], xyz[3*i+2],
                              __int_as_float(cg_z[i]));
}

// Kernel 2: T[row][c] = silu(P[zi]+P[zj]) @ W_vec, row = zi*VOCAB+zj,
// padded stride TPAD. 16 rows per block (R1's proven structure).
__global__ void table_kernel(const float* __restrict__ P,
                             const float* __restrict__ Wvec,
                             float* __restrict__ T) {
    __shared__ float hs[ROWS_PER_BLK][FEAT + 1];
    int t = threadIdx.x;                   // 0..255
    int row0 = blockIdx.x * ROWS_PER_BLK;

    #pragma unroll
    for (int i = 0; i < (ROWS_PER_BLK * FEAT) / 256; ++i) {
        int v = t + i * 256;
        int r = v >> 7, f = v & 127;
        int row = row0 + r;
        int zi = row / VOCAB, zj = row % VOCAB;
        float h = P[zi * FEAT + f] + P[zj * FEAT + f];
        hs[r][f] = h / (1.f + expf(-h));   // silu
    }
    __syncthreads();

    if (t < ROWS_PER_BLK * APC) {
        int r = t / APC, c = t % APC;
        float s = 0.f;
        #pragma unroll 8
        for (int f = 0; f < FEAT; ++f)
            s += hs[r][f] * Wvec[f * APC + c];
        T[(size_t)(row0 + r) * TPAD + c] = s;
    }
}

// Kernel 3: fused segment-sum + reconstruction (R2's proven structure).
// Phase 1: 256 edges/block; ONE 16B xyz4 gather per edge; unit*inv + T-row
//   id packed into LDS float4.
// Phase 2: (cg, channel) threads accumulate 16 edges; output staged in LDS,
//   written as 156 aligned float4 per block (contiguous 2496B).
__global__ void recon_kernel(const float4* __restrict__ xyz4,
                             const int*    __restrict__ nbr,
                             const int*    __restrict__ ca_idx,
                             const float*  __restrict__ T,
                             float* __restrict__ out) {
    __shared__ float4 eu[CG_PER_BLK][DEG + 1];     // padded: conflict-free
    __shared__ float4 xis[CG_PER_BLK];
    __shared__ float  obuf[CG_PER_BLK * APC * 3];  // 624 floats

    int t = threadIdx.x;
    int cg0 = blockIdx.x * CG_PER_BLK;

    {   // phase 1: one edge per thread
        int g = t >> 4, k = t & 15;
        int cg = cg0 + g;
        int e  = cg * DEG + k;             // src = repeat(arange(N_CG), DEG)
        int j  = nbr[2 * e + 1];
        float4 pj = xyz4[j];
        float4 pi = xyz4[cg];
        if (k == 0) xis[g] = pi;
        float dx = pj.x - pi.x, dy = pj.y - pi.y, dz = pj.z - pi.z;
        float inv = 1.f / (sqrtf(dx*dx + dy*dy + dz*dz) + 1e-8f);
        int row = __float_as_int(pi.w) * VOCAB + __float_as_int(pj.w);
        eu[g][k] = make_float4(dx*inv, dy*inv, dz*inv, __int_as_float(row));
    }
    __syncthreads();

    if (t < CG_PER_BLK * APC) {            // phase 2
        int g = t / APC, c = t % APC;
        int cg = cg0 + g;
        float a0 = 0.f, a1 = 0.f, a2 = 0.f;
        #pragma unroll
        for (int k = 0; k < DEG; ++k) {
            float4 u = eu[g][k];
            int row = __float_as_int(u.w);
            float w = T[(size_t)row * TPAD + c];
            a0 += w * u.x; a1 += w * u.y; a2 += w * u.z;
        }
        // ca atom: channel = ca_idx[cg] - first, first = cg*APC
        if (c == ca_idx[cg] - cg * APC) { a0 = 0.f; a1 = 0.f; a2 = 0.f; }
        float4 xi = xis[g];
        obuf[t * 3 + 0] = a0 + xi.x;
        obuf[t * 3 + 1] = a1 + xi.y;
        obuf[t * 3 + 2] = a2 + xi.z;
    }
    __syncthreads();

    if (t < (CG_PER_BLK * APC * 3) / 4) {  // 156 float4, contiguous
        float4* ov = (float4*)(out + (size_t)blockIdx.x * (CG_PER_BLK * APC * 3));
        ov[t] = ((const float4*)obuf)[t];
    }
}

extern "C" void kernel_launch(void* const* d_in, const int* in_sizes, int n_in,
                              void* d_out, int out_size, void* d_ws, size_t ws_size,
                              hipStream_t stream) {
    const float* cg_xyz  = (const float*)d_in[0];
    const float* emb     = (const float*)d_in[1];
    const float* W_msg   = (const float*)d_in[2];
    const float* W_vec   = (const float*)d_in[3];
    const int*   cg_z    = (const int*)d_in[4];
    const int*   nbr     = (const int*)d_in[5];
    const int*   ca_idx  = (const int*)d_in[7];
    float* out = (float*)d_out;

    float*  T    = (float*)d_ws;                                   // 640 KB
    float4* xyz4 = (float4*)((char*)d_ws + (size_t)VOCAB*VOCAB*TPAD*4);  // 800 KB
    float*  P    = (float*)((char*)xyz4 + (size_t)N_CG * 16);      // 51.2 KB

    p_pack_kernel<<<PBLK + PACKB, 256, 0, stream>>>(
        emb, W_msg, cg_xyz, cg_z, P, xyz4);
    table_kernel<<<(VOCAB * VOCAB) / ROWS_PER_BLK, 256, 0, stream>>>(
        P, W_vec, T);
    recon_kernel<<<N_CG / CG_PER_BLK, 256, 0, stream>>>(
        xyz4, nbr, ca_idx, T, out);
}